// Round 18
// baseline (77.321 us; speedup 1.0000x reference)
//
#include <hip/hip_runtime.h>
#include <hip/hip_bf16.h>

#define N_ 4096
#define D_ 768
#define NCLS 128
#define BM 256
#define BN 128
#define BK 64
#define NSTEP 12  // D_/BK

typedef __bf16 bf16x8 __attribute__((ext_vector_type(8)));
typedef float f32x4 __attribute__((ext_vector_type(4)));

#define SBAR() asm volatile("s_barrier" ::: "memory")
#define VMWAIT12() asm volatile("s_waitcnt vmcnt(12)" ::: "memory")
#define LGKM0() asm volatile("s_waitcnt lgkmcnt(0)" ::: "memory")

__device__ __forceinline__ void gload16(const unsigned short* g, unsigned short* l) {
  __builtin_amdgcn_global_load_lds(
      (const __attribute__((address_space(1))) unsigned int*)g,
      (__attribute__((address_space(3))) unsigned int*)l, 16, 0, 0);
}

// Normalize both embedding matrices (blocks [0,N) -> img, [N,2N) -> txt).
// Block 0 zeroes the reduce accumulators.
__global__ __launch_bounds__(192) void normalize_kernel(
    const float* __restrict__ img, const float* __restrict__ txt,
    __hip_bfloat16* __restrict__ img_nb, __hip_bfloat16* __restrict__ txt_nb,
    double* __restrict__ accs, unsigned* __restrict__ cnt) {
  int b = blockIdx.x;
  if (b == 0 && threadIdx.x == 0) {
    accs[0] = 0.0;
    accs[1] = 0.0;
    *cnt = 0u;
  }
  const float* s;
  __hip_bfloat16* d;
  if (b < N_) {
    s = img + (size_t)b * D_;
    d = img_nb + (size_t)b * D_;
  } else {
    s = txt + (size_t)(b - N_) * D_;
    d = txt_nb + (size_t)(b - N_) * D_;
  }
  int tid = threadIdx.x;
  float4 v = ((const float4*)s)[tid];
  float ss = v.x * v.x + v.y * v.y + v.z * v.z + v.w * v.w;
#pragma unroll
  for (int m = 32; m; m >>= 1) ss += __shfl_xor(ss, m);
  __shared__ float wsum[3];
  int lane = tid & 63, w = tid >> 6;
  if (lane == 0) wsum[w] = ss;
  __syncthreads();
  float inv = 1.0f / fmaxf(sqrtf(wsum[0] + wsum[1] + wsum[2]), 1e-8f);
  ushort4 o;
  o.x = __bfloat16_as_ushort(__float2bfloat16(v.x * inv));
  o.y = __bfloat16_as_ushort(__float2bfloat16(v.y * inv));
  o.z = __bfloat16_as_ushort(__float2bfloat16(v.z * inv));
  o.w = __bfloat16_as_ushort(__float2bfloat16(v.w * inv));
  ((ushort4*)d)[tid] = o;
}

// 256x128-tile bf16 GEMM at 256 threads / 4 waves (2x2; per-wave 128x64,
// acc[8][4] f32x4 = 128 VGPR -- 256-thr blocks get >128 VGPR, unlike 512-thr
// which pins at 128 and spills: r4/r5/r17). Staging via global_load_lds
// (zero staging regs), r16 machinery: pre-swizzled global source
// chunk=(l&7)^(row&7) -> linear LDS dest = conflict-free [row][chunk^row&7];
// 2-slot ring, raw s_barrier + counted vmcnt(12); tail restages dead slot.
// 96KB LDS -> 1 block/CU; in-kernel pipeline hides latency. XCD block remap.
__global__ __launch_bounds__(256) void gemm_epi_kernel(
    const unsigned short* __restrict__ A, const unsigned short* __restrict__ B,
    const int* __restrict__ labels, float* __restrict__ row_part,
    float* __restrict__ col_part, float* __restrict__ S_part) {
  __shared__ __align__(16) unsigned short As[2][16384];  // 256 rows x 8 chunks x 8
  __shared__ __align__(16) unsigned short Bs[2][8192];   // 128 rows
  __shared__ int labR[BM], labC[BN];
  __shared__ float rbuf[2][BM], cbuf[2][BN];
  __shared__ float sbuf[4];

  // XCD-aware remap (bijective; grid 512 % 8 == 0): xcd owns 4 consecutive bx
  const int lin = blockIdx.y * 32 + blockIdx.x;
  const int xcd = lin & 7, idx = lin >> 3;
  const int bx = xcd * 4 + (idx & 3), by = idx >> 2;  // bx 0..31, by 0..15

  const int tid = threadIdx.x;
  const int lane = tid & 63, wave = tid >> 6;
  const int wr = wave >> 1, wc = wave & 1;  // 2x2 wave grid; wave owns 128x64
  const int g = lane >> 4, fr = lane & 15;
  const int rowBase = by * BM, colBase = bx * BN;

  labR[tid] = labels[rowBase + tid];
  if (tid < BN) labC[tid] = labels[colBase + tid];
  __syncthreads();  // labels visible before any gload issue

  // staging: wave w, issue j covers rows j*32 + w*8 + (lane>>3); chunk (l&7)^(row&7)
  const int r0 = lane >> 3;
  const int cswz = (lane & 7) ^ (r0 & 7);
  const unsigned short* pa = A + (size_t)(rowBase + wave * 8 + r0) * D_ + cswz * 8;
  const unsigned short* pb = B + (size_t)(colBase + wave * 8 + r0) * D_ + cswz * 8;
  const int dbase = wave * 512;  // (wave*8 rows)*64 ushorts; + j*2048

  // prologue: issue step 0 (8 A + 4 B loads in flight)
#pragma unroll
  for (int j = 0; j < 8; ++j)
    gload16(pa + (size_t)(32 * j) * D_, &As[0][dbase + j * 2048]);
#pragma unroll
  for (int j = 0; j < 4; ++j)
    gload16(pb + (size_t)(32 * j) * D_, &Bs[0][dbase + j * 2048]);

  f32x4 acc[8][4] = {};

  for (int u = 0; u < NSTEP; ++u) {
    SBAR();  // all waves done reading the slot about to be overwritten
    {
      const int su = (u + 1 < NSTEP) ? u + 1 : u;  // tail: restage dead slot
      const size_t kk = (size_t)su * BK;
      const int sl = (u + 1) & 1;
#pragma unroll
      for (int j = 0; j < 8; ++j)
        gload16(pa + (size_t)(32 * j) * D_ + kk, &As[sl][dbase + j * 2048]);
#pragma unroll
      for (int j = 0; j < 4; ++j)
        gload16(pb + (size_t)(32 * j) * D_ + kk, &Bs[sl][dbase + j * 2048]);
    }
    VMWAIT12();  // my step-u 12 loads landed; step-u+1's 12 stay in flight
    SBAR();      // every wave's step-u loads landed: slot u&1 fully valid
    const unsigned short* as_ = As[u & 1];
    const unsigned short* bs_ = Bs[u & 1];
#pragma unroll
    for (int ks = 0; ks < 2; ++ks) {
      const int sw = (ks * 4 + g) ^ (fr & 7);
      bf16x8 bf[4];
#pragma unroll
      for (int n = 0; n < 4; ++n)
        bf[n] = *(const bf16x8*)&bs_[((wc * 64 + n * 16 + fr) * 8 + sw) * 8];
#pragma unroll
      for (int m = 0; m < 8; ++m) {
        bf16x8 af = *(const bf16x8*)&as_[((wr * 128 + m * 16 + fr) * 8 + sw) * 8];
#pragma unroll
        for (int n = 0; n < 4; ++n)
          acc[m][n] = __builtin_amdgcn_mfma_f32_16x16x32_bf16(af, bf[n], acc[m][n], 0, 0, 0);
      }
    }
    LGKM0();  // my ds_reads drained before signaling the next top barrier
  }
  __syncthreads();  // full drain before epilogue

  const float scale = 14.285714285714286f;  // 1/0.07
  float sPart = 0.f;
  float colAcc[4] = {0.f, 0.f, 0.f, 0.f};
#pragma unroll
  for (int m = 0; m < 8; ++m) {
    float ra2[4] = {0.f, 0.f, 0.f, 0.f};
#pragma unroll
    for (int n = 0; n < 4; ++n) {
      int col = wc * 64 + n * 16 + fr;
      int lc = labC[col];
#pragma unroll
      for (int r = 0; r < 4; ++r) {
        float v = acc[m][n][r] * scale;
        float e = __expf(v);
        ra2[r] += e;
        colAcc[n] += e;
        int row = wr * 128 + m * 16 + g * 4 + r;
        if (labR[row] == lc) sPart += v;
      }
    }
#pragma unroll
    for (int r = 0; r < 4; ++r) {
      float x = ra2[r];
      x += __shfl_xor(x, 1);
      x += __shfl_xor(x, 2);
      x += __shfl_xor(x, 4);
      x += __shfl_xor(x, 8);
      if (fr == 0) rbuf[wc][wr * 128 + m * 16 + g * 4 + r] = x;
    }
  }
#pragma unroll
  for (int n = 0; n < 4; ++n) {
    float x = colAcc[n];
    x += __shfl_xor(x, 16);
    x += __shfl_xor(x, 32);
    if (lane < 16) cbuf[wr][wc * 64 + n * 16 + fr] = x;
  }
  float s = sPart;
#pragma unroll
  for (int m = 32; m; m >>= 1) s += __shfl_xor(s, m);
  if (lane == 0) sbuf[wave] = s;
  __syncthreads();
  row_part[(size_t)bx * N_ + rowBase + tid] = rbuf[0][tid] + rbuf[1][tid];
  if (tid < BN)
    col_part[(size_t)by * N_ + colBase + tid] = cbuf[0][tid] + cbuf[1][tid];
  if (tid == 0)
    S_part[by * 32 + bx] = sbuf[0] + sbuf[1] + sbuf[2] + sbuf[3];
}

// Merged final reduction: per-block hist + partials -> device-scope double
// atomics; last-done block writes the scalar loss.
__global__ __launch_bounds__(256) void reduce_kernel(
    const float* __restrict__ row_part, const float* __restrict__ col_part,
    const float* __restrict__ S_part, const int* __restrict__ labels,
    double* __restrict__ accs, unsigned* __restrict__ cnt, float* __restrict__ out) {
  __shared__ int hist[NCLS];
  int tid = threadIdx.x;
  if (tid < NCLS) hist[tid] = 0;
  __syncthreads();
  for (int j = tid; j < N_; j += 256) atomicAdd(&hist[labels[j]], 1);
  __syncthreads();

  int i = blockIdx.x * 256 + tid;  // 0..4095
  float rs = 0.f, cs = 0.f;
#pragma unroll
  for (int b = 0; b < 32; ++b) rs += row_part[(size_t)b * N_ + i];
#pragma unroll
  for (int b = 0; b < 16; ++b) cs += col_part[(size_t)b * N_ + i];
  int c = hist[labels[i]];
  double term = (double)c * ((double)logf(rs) + (double)logf(cs));
  double sterm = (i < 512) ? (double)S_part[i] : 0.0;
#pragma unroll
  for (int m = 32; m; m >>= 1) {
    term += __shfl_xor(term, m);
    sterm += __shfl_xor(sterm, m);
  }
  __shared__ double tbuf[4], sb[4];
  int lane = tid & 63, w = tid >> 6;
  if (lane == 0) { tbuf[w] = term; sb[w] = sterm; }
  __syncthreads();
  if (tid == 0) {
    atomicAdd(&accs[0], tbuf[0] + tbuf[1] + tbuf[2] + tbuf[3]);
    atomicAdd(&accs[1], sb[0] + sb[1] + sb[2] + sb[3]);
    __threadfence();
    unsigned old = atomicAdd(cnt, 1u);
    if (old == 15u) {
      double t = atomicAdd(&accs[0], 0.0);
      double s2 = atomicAdd(&accs[1], 0.0);
      out[0] = (float)((t - 2.0 * s2) / (2.0 * (double)N_));
    }
  }
}

extern "C" void kernel_launch(void* const* d_in, const int* in_sizes, int n_in,
                              void* d_out, int out_size, void* d_ws, size_t ws_size,
                              hipStream_t stream) {
  const float* img = (const float*)d_in[0];
  const float* txt = (const float*)d_in[1];
  const int* labels = (const int*)d_in[2];
  float* out = (float*)d_out;
  char* ws = (char*)d_ws;

  // workspace layout (bytes)
  __hip_bfloat16* img_nb = (__hip_bfloat16*)(ws);             //  6,291,456
  __hip_bfloat16* txt_nb = (__hip_bfloat16*)(ws + 6291456);   //  6,291,456
  float* row_part = (float*)(ws + 12582912);                  //    524,288 (32 x 4096)
  float* col_part = (float*)(ws + 13107200);                  //    262,144 (16 x 4096)
  float* S_part = (float*)(ws + 13369344);                    //      2,048
  double* accs = (double*)(ws + 13371392);                    //  16 (+cnt 4)
  unsigned* cnt = (unsigned*)(ws + 13371408);

  normalize_kernel<<<2 * N_, 192, 0, stream>>>(img, txt, img_nb, txt_nb, accs, cnt);
  gemm_epi_kernel<<<dim3(32, 16), 256, 0, stream>>>(
      (const unsigned short*)img_nb, (const unsigned short*)txt_nb, labels,
      row_part, col_part, S_part);
  reduce_kernel<<<16, 256, 0, stream>>>(row_part, col_part, S_part, labels, accs, cnt, out);
}

// Round 19
// 59.726 us; speedup vs baseline: 1.2946x; 1.2946x over previous
//
#include <hip/hip_runtime.h>
#include <hip/hip_bf16.h>

#define N_ 4096
#define D_ 768
#define NCLS 128
#define BM 128
#define BN 128
#define BK 32
#define NSTEP 24  // D_/BK

typedef __bf16 bf16x8 __attribute__((ext_vector_type(8)));
typedef float f32x4 __attribute__((ext_vector_type(4)));

#define SBAR() asm volatile("s_barrier" ::: "memory")
#define VMWAIT2() asm volatile("s_waitcnt vmcnt(2)" ::: "memory")
#define LGKM0() asm volatile("s_waitcnt lgkmcnt(0)" ::: "memory")

__device__ __forceinline__ void gload16(const unsigned short* g, unsigned short* l) {
  __builtin_amdgcn_global_load_lds(
      (const __attribute__((address_space(1))) unsigned int*)g,
      (__attribute__((address_space(3))) unsigned int*)l, 16, 0, 0);
}

// Normalize both embedding matrices (blocks [0,N) -> img, [N,2N) -> txt).
// Block 0 zeroes the reduce accumulators.
__global__ __launch_bounds__(192) void normalize_kernel(
    const float* __restrict__ img, const float* __restrict__ txt,
    __hip_bfloat16* __restrict__ img_nb, __hip_bfloat16* __restrict__ txt_nb,
    double* __restrict__ accs, unsigned* __restrict__ cnt) {
  int b = blockIdx.x;
  if (b == 0 && threadIdx.x == 0) {
    accs[0] = 0.0;
    accs[1] = 0.0;
    *cnt = 0u;
  }
  const float* s;
  __hip_bfloat16* d;
  if (b < N_) {
    s = img + (size_t)b * D_;
    d = img_nb + (size_t)b * D_;
  } else {
    s = txt + (size_t)(b - N_) * D_;
    d = txt_nb + (size_t)(b - N_) * D_;
  }
  int tid = threadIdx.x;
  float4 v = ((const float4*)s)[tid];
  float ss = v.x * v.x + v.y * v.y + v.z * v.z + v.w * v.w;
#pragma unroll
  for (int m = 32; m; m >>= 1) ss += __shfl_xor(ss, m);
  __shared__ float wsum[3];
  int lane = tid & 63, w = tid >> 6;
  if (lane == 0) wsum[w] = ss;
  __syncthreads();
  float inv = 1.0f / fmaxf(sqrtf(wsum[0] + wsum[1] + wsum[2]), 1e-8f);
  ushort4 o;
  o.x = __bfloat16_as_ushort(__float2bfloat16(v.x * inv));
  o.y = __bfloat16_as_ushort(__float2bfloat16(v.y * inv));
  o.z = __bfloat16_as_ushort(__float2bfloat16(v.z * inv));
  o.w = __bfloat16_as_ushort(__float2bfloat16(v.w * inv));
  ((ushort4*)d)[tid] = o;
}

// 128x128-tile bf16 GEMM at MAX OCCUPANCY: 512 thr / 8 waves (2x4 grid,
// per-wave 64x32 output -> acc[4][2] f32x4 = 32 VGPR, safely under the
// 512-thr 128-VGPR allocator pin). BK=32 dbuf = 32KB LDS -> 4 blocks/CU x
// 8 waves = 32 waves/CU (HW cap); all 1024 blocks co-resident -- stalls of
// one block fill with another's MFMA. Staging: r16's gload_lds machinery,
// source chunk pre-swizzled (t&3)^((row>>1)&3) within each 64B row (same
// cache line; <=2-way banks = free on write AND read). 2-slot ring, raw
// s_barrier + counted vmcnt(2); tail restages dead slot. XCD block remap.
__global__ __launch_bounds__(512) void gemm_epi_kernel(
    const unsigned short* __restrict__ A, const unsigned short* __restrict__ B,
    const int* __restrict__ labels, float* __restrict__ row_part,
    float* __restrict__ col_part, float* __restrict__ S_part) {
  __shared__ __align__(16) unsigned short As[2][4096];  // [slot][row*4+chunk][8]
  __shared__ __align__(16) unsigned short Bs[2][4096];
  __shared__ int labR[BM], labC[BN];
  __shared__ float rbuf[4][BM], cbuf[2][BN];
  __shared__ float sbuf[8];

  // XCD-aware remap (bijective; grid 1024 % 8 == 0)
  const int lin = blockIdx.y * 32 + blockIdx.x;
  const int xcd = lin & 7, idx = lin >> 3;
  const int bx = xcd * 4 + (idx & 3), by = idx >> 2;

  const int tid = threadIdx.x;
  const int lane = tid & 63, wave = tid >> 6;
  const int wr = wave >> 2, wc = wave & 3;  // wave owns rows [wr*64,+64), cols [wc*32,+32)
  const int g = lane >> 4, fr = lane & 15;
  const int rowBase = by * BM, colBase = bx * BN;

  if (tid < BM) labR[tid] = labels[rowBase + tid];
  else if (tid < BM + BN) labC[tid - BM] = labels[colBase + tid - BM];
  __syncthreads();  // labels visible before any gload issue

  // staging: thread t -> row t>>2 (0..127), global chunk (t&3)^((row>>1)&3).
  // Linear LDS dest (wave*64 + lane)*16B realizes [row][physchunk] where
  // physchunk p holds global chunk p^s(row); reader wants chunk g -> p = g^s(r).
  const int srow = tid >> 2;
  const int cswz = (tid & 3) ^ ((srow >> 1) & 3);
  const unsigned short* pa = A + (size_t)(rowBase + srow) * D_ + cswz * 8;
  const unsigned short* pb = B + (size_t)(colBase + srow) * D_ + cswz * 8;
  const int dpos = (wave * 64) * 8;  // ushort idx of this wave's 64-chunk span

  // prologue: issue step 0 into slot 0 (2 loads in flight per thread)
  gload16(pa, &As[0][dpos]);
  gload16(pb, &Bs[0][dpos]);

  f32x4 acc[4][2] = {};

  for (int u = 0; u < NSTEP; ++u) {
    SBAR();  // all waves done reading the slot about to be overwritten
    {
      const int su = (u + 1 < NSTEP) ? u + 1 : u;  // tail: restage dead slot
      const size_t kk = (size_t)su * BK;
      const int sl = (u + 1) & 1;
      gload16(pa + kk, &As[sl][dpos]);
      gload16(pb + kk, &Bs[sl][dpos]);
    }
    VMWAIT2();  // my step-u loads landed; step-u+1's 2 stay in flight
    SBAR();     // every wave's step-u loads landed: slot u&1 fully valid
    const unsigned short* as_ = As[u & 1];
    const unsigned short* bs_ = Bs[u & 1];
    // fragment: row r' = base + fr; s(r') = ((fr>>1)&3) (base multiples of 16)
    const int sw = g ^ ((fr >> 1) & 3);
    bf16x8 af[4], bf[2];
#pragma unroll
    for (int m = 0; m < 4; ++m)
      af[m] = *(const bf16x8*)&as_[((wr * 64 + m * 16 + fr) * 4 + sw) * 8];
#pragma unroll
    for (int n = 0; n < 2; ++n)
      bf[n] = *(const bf16x8*)&bs_[((wc * 32 + n * 16 + fr) * 4 + sw) * 8];
#pragma unroll
    for (int m = 0; m < 4; ++m)
#pragma unroll
      for (int n = 0; n < 2; ++n)
        acc[m][n] = __builtin_amdgcn_mfma_f32_16x16x32_bf16(af[m], bf[n], acc[m][n], 0, 0, 0);
    LGKM0();  // my ds_reads drained before signaling the next top barrier
  }
  __syncthreads();  // full drain before epilogue

  const float scale = 14.285714285714286f;  // 1/0.07
  float sPart = 0.f;
  float colAcc[2] = {0.f, 0.f};
#pragma unroll
  for (int m = 0; m < 4; ++m) {
    float ra2[4] = {0.f, 0.f, 0.f, 0.f};
#pragma unroll
    for (int n = 0; n < 2; ++n) {
      int col = wc * 32 + n * 16 + fr;
      int lc = labC[col];
#pragma unroll
      for (int r = 0; r < 4; ++r) {
        float v = acc[m][n][r] * scale;
        float e = __expf(v);
        ra2[r] += e;
        colAcc[n] += e;
        int row = wr * 64 + m * 16 + g * 4 + r;
        if (labR[row] == lc) sPart += v;
      }
    }
#pragma unroll
    for (int r = 0; r < 4; ++r) {
      float x = ra2[r];
      x += __shfl_xor(x, 1);
      x += __shfl_xor(x, 2);
      x += __shfl_xor(x, 4);
      x += __shfl_xor(x, 8);
      if (fr == 0) rbuf[wc][wr * 64 + m * 16 + g * 4 + r] = x;
    }
  }
#pragma unroll
  for (int n = 0; n < 2; ++n) {
    float x = colAcc[n];
    x += __shfl_xor(x, 16);
    x += __shfl_xor(x, 32);
    if (g == 0) cbuf[wr][wc * 32 + n * 16 + fr] = x;
  }
  float s = sPart;
#pragma unroll
  for (int m = 32; m; m >>= 1) s += __shfl_xor(s, m);
  if (lane == 0) sbuf[wave] = s;
  __syncthreads();
  if (tid < BM)
    row_part[(size_t)bx * N_ + rowBase + tid] =
        rbuf[0][tid] + rbuf[1][tid] + rbuf[2][tid] + rbuf[3][tid];
  else if (tid < BM + BN) {
    int c = tid - BM;
    col_part[(size_t)by * N_ + colBase + c] = cbuf[0][c] + cbuf[1][c];
  }
  if (tid == 0)
    S_part[by * 32 + bx] =
        sbuf[0] + sbuf[1] + sbuf[2] + sbuf[3] + sbuf[4] + sbuf[5] + sbuf[6] + sbuf[7];
}

// Merged final reduction: per-block hist + partials -> device-scope double
// atomics; last-done block writes the scalar loss.
__global__ __launch_bounds__(256) void reduce_kernel(
    const float* __restrict__ row_part, const float* __restrict__ col_part,
    const float* __restrict__ S_part, const int* __restrict__ labels,
    double* __restrict__ accs, unsigned* __restrict__ cnt, float* __restrict__ out) {
  __shared__ int hist[NCLS];
  int tid = threadIdx.x;
  if (tid < NCLS) hist[tid] = 0;
  __syncthreads();
  for (int j = tid; j < N_; j += 256) atomicAdd(&hist[labels[j]], 1);
  __syncthreads();

  int i = blockIdx.x * 256 + tid;  // 0..4095
  float rs = 0.f, cs = 0.f;
#pragma unroll
  for (int b = 0; b < 32; ++b) {
    rs += row_part[(size_t)b * N_ + i];
    cs += col_part[(size_t)b * N_ + i];
  }
  int c = hist[labels[i]];
  double term = (double)c * ((double)logf(rs) + (double)logf(cs));
  double sterm = (i < 1024) ? (double)S_part[i] : 0.0;
#pragma unroll
  for (int m = 32; m; m >>= 1) {
    term += __shfl_xor(term, m);
    sterm += __shfl_xor(sterm, m);
  }
  __shared__ double tbuf[4], sb[4];
  int lane = tid & 63, w = tid >> 6;
  if (lane == 0) { tbuf[w] = term; sb[w] = sterm; }
  __syncthreads();
  if (tid == 0) {
    atomicAdd(&accs[0], tbuf[0] + tbuf[1] + tbuf[2] + tbuf[3]);
    atomicAdd(&accs[1], sb[0] + sb[1] + sb[2] + sb[3]);
    __threadfence();
    unsigned old = atomicAdd(cnt, 1u);
    if (old == 15u) {
      double t = atomicAdd(&accs[0], 0.0);
      double s2 = atomicAdd(&accs[1], 0.0);
      out[0] = (float)((t - 2.0 * s2) / (2.0 * (double)N_));
    }
  }
}

extern "C" void kernel_launch(void* const* d_in, const int* in_sizes, int n_in,
                              void* d_out, int out_size, void* d_ws, size_t ws_size,
                              hipStream_t stream) {
  const float* img = (const float*)d_in[0];
  const float* txt = (const float*)d_in[1];
  const int* labels = (const int*)d_in[2];
  float* out = (float*)d_out;
  char* ws = (char*)d_ws;

  // workspace layout (bytes)
  __hip_bfloat16* img_nb = (__hip_bfloat16*)(ws);             //  6,291,456
  __hip_bfloat16* txt_nb = (__hip_bfloat16*)(ws + 6291456);   //  6,291,456
  float* row_part = (float*)(ws + 12582912);                  //    524,288 (32 x 4096)
  float* col_part = (float*)(ws + 13107200);                  //    524,288
  float* S_part = (float*)(ws + 13631488);                    //      4,096
  double* accs = (double*)(ws + 13635584);                    //  16 (+cnt 4)
  unsigned* cnt = (unsigned*)(ws + 13635600);

  normalize_kernel<<<2 * N_, 192, 0, stream>>>(img, txt, img_nb, txt_nb, accs, cnt);
  gemm_epi_kernel<<<dim3(32, 32), 512, 0, stream>>>(
      (const unsigned short*)img_nb, (const unsigned short*)txt_nb, labels,
      row_part, col_part, S_part);
  reduce_kernel<<<16, 256, 0, stream>>>(row_part, col_part, S_part, labels, accs, cnt, out);
}